// Round 1
// baseline (395.908 us; speedup 1.0000x reference)
//
#include <hip/hip_runtime.h>

typedef unsigned int u32;
typedef unsigned long long u64;

#define BATCH 32
#define NPRI  200000
#define TOPK  200
#define NBINS 16384          // bin = float_bits >> 17 (positive floats only)
#define CAP   4096           // max candidates kept per image
#define ZWORDS (BATCH*NBINS + 64)   // hist + thrbin(32) + ncand(32)
#define OUTN  (BATCH*2*TOPK*5)

// ---------------- zero ws + output ----------------
__global__ void k_zero(u32* __restrict__ wsw, float* __restrict__ out) {
  int stride = gridDim.x * blockDim.x;
  for (int i = blockIdx.x*blockDim.x + threadIdx.x; i < ZWORDS + OUTN; i += stride) {
    if (i < ZWORDS) wsw[i] = 0u;
    else out[i - ZWORDS] = 0.0f;
  }
}

// ---------------- per-image score histogram (LDS-privatized) ----------------
__global__ __launch_bounds__(256) void k_hist(const float* __restrict__ conf,
                                              u32* __restrict__ hist) {
  __shared__ u32 lh[NBINS];              // 64 KB
  for (int b = threadIdx.x; b < NBINS; b += 256) lh[b] = 0u;
  __syncthreads();
  const int img = blockIdx.y;
  const float4* cp = ((const float4*)conf) + (size_t)img * (NPRI/2);
  const int M = NPRI/2;
  for (int i = blockIdx.x*256 + threadIdx.x; i < M; i += gridDim.x*256) {
    float4 v = cp[i];                    // two (c0,c1) pairs
    if (v.y > 0.01f) atomicAdd(&lh[__float_as_uint(v.y) >> 17], 1u);
    if (v.w > 0.01f) atomicAdd(&lh[__float_as_uint(v.w) >> 17], 1u);
  }
  __syncthreads();
  u32* h = hist + (size_t)img * NBINS;
  for (int b = threadIdx.x; b < NBINS; b += 256) {
    u32 v = lh[b];
    if (v) atomicAdd(&h[b], v);
  }
}

// ---------------- find per-image threshold bin (radix-select) ----------------
__global__ __launch_bounds__(256) void k_thresh(const u32* __restrict__ hist,
                                                u32* __restrict__ thrbin) {
  const int img = blockIdx.x;
  const int tid = threadIdx.x;
  const u32* h = hist + (size_t)img * NBINS;
  __shared__ u32 sums[256];
  __shared__ u32 s_c, s_above;
  __shared__ u32 binv[64];
  u32 acc = 0;
  const int base = tid * 64;
  for (int b = 0; b < 64; ++b) acc += h[base + b];
  sums[tid] = acc;
  __syncthreads();
  // inclusive suffix scan over 256 chunk sums
  for (int off = 1; off < 256; off <<= 1) {
    u32 v = (tid + off < 256) ? sums[tid + off] : 0u;
    __syncthreads();
    sums[tid] += v;
    __syncthreads();
  }
  if (tid == 0) s_c = 0xFFFFFFFFu;
  __syncthreads();
  u32 mine = sums[tid];
  u32 nxt  = (tid < 255) ? sums[tid + 1] : 0u;
  if (mine >= TOPK && nxt < TOPK) { s_c = tid; s_above = nxt; }  // unique
  __syncthreads();
  if (s_c == 0xFFFFFFFFu) {            // fewer than TOPK scores above conf-thr
    if (tid == 0) thrbin[img] = 0u;
    return;
  }
  if (tid < 64) binv[tid] = h[s_c * 64 + tid];
  __syncthreads();
  if (tid == 0) {
    u32 run = s_above, T = 0u;
    for (int b = 63; b >= 0; --b) {
      run += binv[b];
      if (run >= TOPK) { T = s_c * 64 + (u32)b; break; }
    }
    thrbin[img] = T;
  }
}

// ---------------- compact candidates >= threshold bin ----------------
__global__ __launch_bounds__(256) void k_compact(const float* __restrict__ conf,
                                                 const u32* __restrict__ thrbin,
                                                 u32* __restrict__ ncand,
                                                 u64* __restrict__ cand) {
  const int img = blockIdx.y;
  const u32 T = thrbin[img];
  const float4* cp = ((const float4*)conf) + (size_t)img * (NPRI/2);
  u64* cd = cand + (size_t)img * CAP;
  const int M = NPRI/2;
  for (int i = blockIdx.x*256 + threadIdx.x; i < M; i += gridDim.x*256) {
    float4 v = cp[i];
    if (v.y > 0.01f) {
      u32 bits = __float_as_uint(v.y);
      if ((bits >> 17) >= T) {
        u32 p = atomicAdd(&ncand[img], 1u);
        if (p < CAP) cd[p] = ((u64)bits << 32) | (u64)(0xFFFFFFFFu - (u32)(2*i));
      }
    }
    if (v.w > 0.01f) {
      u32 bits = __float_as_uint(v.w);
      if ((bits >> 17) >= T) {
        u32 p = atomicAdd(&ncand[img], 1u);
        if (p < CAP) cd[p] = ((u64)bits << 32) | (u64)(0xFFFFFFFFu - (u32)(2*i+1));
      }
    }
  }
}

// ---------------- sort + decode + NMS + emit ----------------
__global__ __launch_bounds__(256) void k_nms(const float* __restrict__ loc,
                                             const float* __restrict__ priors,
                                             const u32* __restrict__ ncand,
                                             const u64* __restrict__ cand,
                                             float* __restrict__ out) {
  const int img = blockIdx.x;
  const int tid = threadIdx.x;
  __shared__ u64   keys[CAP];          // 32 KB
  __shared__ float4 sbox[TOPK];
  __shared__ float  sscore[TOPK];
  __shared__ u64    sovl[TOPK][4];     // suppression bitmasks
  __shared__ u32    skept[TOPK];
  __shared__ u64    sact[4];
  __shared__ u32    sK;

  u32 nc = ncand[img]; if (nc > CAP) nc = CAP;
  u32 P = 256; while (P < nc) P <<= 1;          // pow2 padded size, >= 256
  const u64* cd = cand + (size_t)img * CAP;
  for (u32 t = tid; t < P; t += 256) keys[t] = (t < nc) ? cd[t] : 0ull;
  __syncthreads();
  // bitonic sort descending (key = score_bits<<32 | ~index -> stable top-k order)
  for (u32 k = 2; k <= P; k <<= 1) {
    for (u32 j = k >> 1; j > 0; j >>= 1) {
      for (u32 t = tid; t < P; t += 256) {
        u32 x = t ^ j;
        if (x > t) {
          u64 a = keys[t], b = keys[x];
          bool up = ((t & k) == 0);
          if (up ? (a < b) : (a > b)) { keys[t] = b; keys[x] = a; }
        }
      }
      __syncthreads();
    }
  }
  // take top-200, decode boxes
  bool valid = false;
  float4 bx = make_float4(0.f, 0.f, 0.f, 0.f);
  float sc = 0.f;
  if (tid < TOPK) {
    u64 key = keys[tid];
    sc = __uint_as_float((u32)(key >> 32));
    valid = (sc > 0.01f);
    if (valid) {
      u32 idx = 0xFFFFFFFFu - (u32)(key & 0xFFFFFFFFull);
      float4 l = ((const float4*)loc)[(size_t)img * NPRI + idx];
      float4 p = ((const float4*)priors)[idx];
      float cx = p.x + (l.x * 0.1f) * p.z;
      float cy = p.y + (l.y * 0.1f) * p.w;
      float w  = p.z * expf(l.z * 0.2f);
      float h  = p.w * expf(l.w * 0.2f);
      bx = make_float4(cx - w * 0.5f, cy - h * 0.5f, cx + w * 0.5f, cy + h * 0.5f);
    }
    sbox[tid] = bx;
    sscore[tid] = sc;
  }
  u64 bal = __ballot(valid);                    // wave w covers slots [64w,64w+64)
  if ((tid & 63) == 0) sact[tid >> 6] = bal;
  __syncthreads();
  // all-pairs suppression masks (reference: suppress when !(iou <= 0.45), NaN suppresses)
  if (tid < TOPK) {
    float4 bi = sbox[tid];
    float ai = (bi.z - bi.x) * (bi.w - bi.y);
    u64 m0 = 0, m1 = 0, m2 = 0, m3 = 0;
    for (int j = 0; j < TOPK; ++j) {
      float4 bj = sbox[j];
      float ltx = fmaxf(bi.x, bj.x), lty = fmaxf(bi.y, bj.y);
      float rbx = fminf(bi.z, bj.z), rby = fminf(bi.w, bj.w);
      float w = fmaxf(rbx - ltx, 0.f), h = fmaxf(rby - lty, 0.f);
      float inter = w * h;
      float aj = (bj.z - bj.x) * (bj.w - bj.y);
      float uni = ai + aj - inter;
      float iou = inter / uni;
      if (!(iou <= 0.45f)) {
        if      (j < 64)  m0 |= 1ull << j;
        else if (j < 128) m1 |= 1ull << (j - 64);
        else if (j < 192) m2 |= 1ull << (j - 128);
        else              m3 |= 1ull << (j - 192);
      }
    }
    sovl[tid][0] = m0; sovl[tid][1] = m1; sovl[tid][2] = m2; sovl[tid][3] = m3;
  }
  __syncthreads();
  // serial greedy sweep over 200 slots (cheap: bitmask ANDs)
  if (tid == 0) {
    u64 a0 = sact[0], a1 = sact[1], a2 = sact[2], a3 = sact[3];
    int K = 0;
    for (int i = 0; i < TOPK; ++i) {
      u64 r0 = sovl[i][0], r1 = sovl[i][1], r2 = sovl[i][2], r3 = sovl[i][3];
      u64 w = (i & 64) ? ((i & 128) ? a3 : a1) : ((i & 128) ? a2 : a0);
      if ((w >> (i & 63)) & 1ull) {
        skept[K++] = (u32)i;
        a0 &= ~r0; a1 &= ~r1; a2 &= ~r2; a3 &= ~r3;
      }
    }
    sK = (u32)K;
  }
  __syncthreads();
  if (tid < (int)sK) {
    u32 slot = skept[tid];
    float4 b = sbox[slot];
    size_t base = (((size_t)img * 2 + 1) * TOPK + (size_t)tid) * 5;
    out[base + 0] = sscore[slot];
    out[base + 1] = b.x; out[base + 2] = b.y;
    out[base + 3] = b.z; out[base + 4] = b.w;
  }
}

extern "C" void kernel_launch(void* const* d_in, const int* in_sizes, int n_in,
                              void* d_out, int out_size, void* d_ws, size_t ws_size,
                              hipStream_t stream) {
  const float* loc    = (const float*)d_in[0];
  const float* conf   = (const float*)d_in[1];
  const float* priors = (const float*)d_in[2];
  float* out = (float*)d_out;

  u32* wsw    = (u32*)d_ws;
  u32* hist   = wsw;
  u32* thrbin = wsw + (size_t)BATCH * NBINS;
  u32* ncand  = thrbin + BATCH;
  u64* cand   = (u64*)((char*)d_ws + (size_t)(BATCH * NBINS + 64) * 4);

  k_zero   <<<512, 256, 0, stream>>>(wsw, out);
  k_hist   <<<dim3(16, BATCH), 256, 0, stream>>>(conf, hist);
  k_thresh <<<BATCH, 256, 0, stream>>>(hist, thrbin);
  k_compact<<<dim3(16, BATCH), 256, 0, stream>>>(conf, thrbin, ncand, cand);
  k_nms    <<<BATCH, 256, 0, stream>>>(loc, priors, ncand, cand, out);
}

// Round 3
// 258.774 us; speedup vs baseline: 1.5299x; 1.5299x over previous
//
#include <hip/hip_runtime.h>

typedef unsigned int u32;
typedef unsigned long long u64;

#define BATCH 32
#define NPRI  200000
#define TOPK  200
#define NBINS 16384            // fallback histogram bins: bin = float_bits >> 17
#define CAP   4096             // max candidates per image
#define PRE_BITS 0x3F7C0000u   // bits of 0.984375f; capture scores >= this
#define LBUF  512              // per-block LDS candidate buffer
#define S16   16               // counter padding (64B lines)

// ws layout (u32 words)
#define W_HIST   0
#define W_NCAND  (BATCH*NBINS)
#define W_CNT001 (W_NCAND + BATCH*S16)
#define W_FLAGS  (W_CNT001 + BATCH*S16)
#define W_THR    (W_FLAGS + BATCH)
#define ZWORDS   (W_THR + BATCH)
#define OUTN     (BATCH*2*TOPK*5)

// ---------------- zero ws + output ----------------
__global__ void k_zero(u32* __restrict__ wsw, float* __restrict__ out) {
  int stride = gridDim.x * blockDim.x;
  for (int i = blockIdx.x*blockDim.x + threadIdx.x; i < ZWORDS + OUTN; i += stride) {
    if (i < ZWORDS) wsw[i] = 0u;
    else out[i - ZWORDS] = 0.0f;
  }
}

// ------- hot path: single BW pass, capture scores >= 0.984375, count positives -------
__global__ __launch_bounds__(256) void k_cap(const float* __restrict__ conf,
                                             u32* __restrict__ ncand,
                                             u32* __restrict__ cnt001,
                                             u64* __restrict__ cand,
                                             u32* __restrict__ flags) {
  __shared__ u64 lbuf[LBUF];          // 4 KB
  __shared__ u32 lcnt, lbase, lc001;
  if (threadIdx.x == 0) { lcnt = 0u; lc001 = 0u; }
  __syncthreads();
  const int img = blockIdx.y;
  const float4* cp = ((const float4*)conf) + (size_t)img * (NPRI/2);
  u32 my001 = 0;
  for (int i = blockIdx.x*256 + threadIdx.x; i < NPRI/2; i += gridDim.x*256) {
    float4 v = cp[i];
    if (v.y > 0.01f) {
      ++my001;
      u32 bits = __float_as_uint(v.y);
      if (bits >= PRE_BITS) {
        u32 p = atomicAdd(&lcnt, 1u);
        if (p < LBUF) lbuf[p] = ((u64)bits << 32) | (u64)(0xFFFFFFFFu - (u32)(2*i));
      }
    }
    if (v.w > 0.01f) {
      ++my001;
      u32 bits = __float_as_uint(v.w);
      if (bits >= PRE_BITS) {
        u32 p = atomicAdd(&lcnt, 1u);
        if (p < LBUF) lbuf[p] = ((u64)bits << 32) | (u64)(0xFFFFFFFFu - (u32)(2*i+1));
      }
    }
  }
  atomicAdd(&lc001, my001);
  __syncthreads();
  if (threadIdx.x == 0) {
    atomicAdd(&cnt001[img * S16], lc001);
    u32 n = lcnt;
    if (n > LBUF) { n = LBUF; atomicOr(&flags[img], 1u); }
    lbase = atomicAdd(&ncand[img * S16], n);
    lcnt = n;
  }
  __syncthreads();
  u64* cd = cand + (size_t)img * CAP;
  u32 n = lcnt, base = lbase;
  for (u32 t = threadIdx.x; t < n; t += 256) {
    u32 p = base + t;
    if (p < CAP) cd[p] = lbuf[t];
    else atomicOr(&flags[img], 1u);
  }
}

// ------- decide per-image fallback (tiny) -------
__global__ void k_flag(u32* __restrict__ ncand, const u32* __restrict__ cnt001,
                       u32* __restrict__ flags) {
  int img = threadIdx.x;
  if (img < BATCH) {
    u32 nc = ncand[img * S16];
    u32 c1 = cnt001[img * S16];
    if (flags[img] != 0u || (nc < TOPK && nc < c1)) {
      flags[img] = 1u;
      ncand[img * S16] = 0u;        // fallback will recapture
    } else {
      flags[img] = 0u;
    }
  }
}

// ------- fallback histogram (gated; no-op on this data) -------
__global__ __launch_bounds__(256) void k_hist2(const float* __restrict__ conf,
                                               const u32* __restrict__ flags,
                                               u32* __restrict__ hist) {
  const int img = blockIdx.y;
  if (flags[img] == 0u) return;             // uniform per block
  __shared__ u32 lh[NBINS/2];               // 32 KB, packed u16 pairs
  for (int b = threadIdx.x; b < NBINS/2; b += 256) lh[b] = 0u;
  __syncthreads();
  const float4* cp = ((const float4*)conf) + (size_t)img * (NPRI/2);
  for (int i = blockIdx.x*256 + threadIdx.x; i < NPRI/2; i += gridDim.x*256) {
    float4 v = cp[i];
    if (v.y > 0.01f) { u32 b = __float_as_uint(v.y) >> 17; atomicAdd(&lh[b >> 1], 1u << ((b & 1) * 16)); }
    if (v.w > 0.01f) { u32 b = __float_as_uint(v.w) >> 17; atomicAdd(&lh[b >> 1], 1u << ((b & 1) * 16)); }
  }
  __syncthreads();
  u32* h = hist + (size_t)img * NBINS;
  for (int b = threadIdx.x; b < NBINS/2; b += 256) {
    u32 v = lh[b];
    if (v & 0xFFFFu) atomicAdd(&h[2*b],     v & 0xFFFFu);
    if (v >> 16)     atomicAdd(&h[2*b + 1], v >> 16);
  }
}

// ------- fallback exact threshold bin (gated) -------
__global__ __launch_bounds__(256) void k_thresh2(const u32* __restrict__ hist,
                                                 const u32* __restrict__ flags,
                                                 u32* __restrict__ thrbin) {
  const int img = blockIdx.x;
  const int tid = threadIdx.x;
  if (flags[img] == 0u) { if (tid == 0) thrbin[img] = 0u; return; }
  const u32* h = hist + (size_t)img * NBINS;
  __shared__ u32 sums[256], binv[64];
  __shared__ u32 s_c, s_above;
  u32 acc = 0;
  for (int b = 0; b < 64; ++b) acc += h[tid*64 + b];
  sums[tid] = acc;
  if (tid == 0) s_c = 0xFFFFFFFFu;
  __syncthreads();
  for (int off = 1; off < 256; off <<= 1) {
    u32 v = (tid + off < 256) ? sums[tid + off] : 0u;
    __syncthreads();
    sums[tid] += v;
    __syncthreads();
  }
  u32 mine = sums[tid], nxt = (tid < 255) ? sums[tid + 1] : 0u;
  if (mine >= TOPK && nxt < TOPK) { s_c = tid; s_above = nxt; }
  __syncthreads();
  if (s_c == 0xFFFFFFFFu) { if (tid == 0) thrbin[img] = 0u; return; }
  if (tid < 64) binv[tid] = h[s_c*64 + tid];
  __syncthreads();
  if (tid == 0) {
    u32 run = s_above, T = 0u;
    for (int b = 63; b >= 0; --b) {
      run += binv[b];
      if (run >= TOPK) { T = s_c*64 + (u32)b; break; }
    }
    thrbin[img] = T;
  }
}

// ------- fallback capture >= threshold bin (gated) -------
__global__ __launch_bounds__(256) void k_compact2(const float* __restrict__ conf,
                                                  const u32* __restrict__ flags,
                                                  const u32* __restrict__ thrbin,
                                                  u32* __restrict__ ncand,
                                                  u64* __restrict__ cand) {
  const int img = blockIdx.y;
  if (flags[img] == 0u) return;
  const u32 T = thrbin[img];
  __shared__ u64 lbuf[1024];          // 8 KB
  __shared__ u32 lcnt, lbase;
  if (threadIdx.x == 0) lcnt = 0u;
  __syncthreads();
  const float4* cp = ((const float4*)conf) + (size_t)img * (NPRI/2);
  u64* cd = cand + (size_t)img * CAP;
  for (int i = blockIdx.x*256 + threadIdx.x; i < NPRI/2; i += gridDim.x*256) {
    float4 v = cp[i];
    if (v.y > 0.01f) {
      u32 bits = __float_as_uint(v.y);
      if ((bits >> 17) >= T) {
        u32 p = atomicAdd(&lcnt, 1u);
        if (p < 1024) lbuf[p] = ((u64)bits << 32) | (u64)(0xFFFFFFFFu - (u32)(2*i));
      }
    }
    if (v.w > 0.01f) {
      u32 bits = __float_as_uint(v.w);
      if ((bits >> 17) >= T) {
        u32 p = atomicAdd(&lcnt, 1u);
        if (p < 1024) lbuf[p] = ((u64)bits << 32) | (u64)(0xFFFFFFFFu - (u32)(2*i+1));
      }
    }
  }
  __syncthreads();
  if (threadIdx.x == 0) {
    u32 n = lcnt; if (n > 1024u) n = 1024u;
    lbase = atomicAdd(&ncand[img * S16], n);
    lcnt = n;
  }
  __syncthreads();
  u32 n = lcnt, base = lbase;
  for (u32 t = threadIdx.x; t < n; t += 256) {
    u32 p = base + t;
    if (p < CAP) cd[p] = lbuf[t];
  }
}

// ---------------- sort + decode + NMS + emit ----------------
__global__ __launch_bounds__(256) void k_nms(const float* __restrict__ loc,
                                             const float* __restrict__ priors,
                                             const u32* __restrict__ ncand,
                                             const u64* __restrict__ cand,
                                             float* __restrict__ out) {
  const int img = blockIdx.x;
  const int tid = threadIdx.x;
  __shared__ u64    keys[CAP];          // 32 KB
  __shared__ float4 sbox[TOPK];
  __shared__ float  sscore[TOPK];
  __shared__ u64    sovl[TOPK][4];
  __shared__ u32    skept[TOPK];
  __shared__ u64    sact[4];
  __shared__ u32    sK;

  u32 nc = ncand[img * S16]; if (nc > CAP) nc = CAP;
  u32 P = 256; while (P < nc) P <<= 1;
  const u64* cd = cand + (size_t)img * CAP;
  for (u32 t = tid; t < P; t += 256) keys[t] = (t < nc) ? cd[t] : 0ull;
  __syncthreads();
  // bitonic sort descending (key = score_bits<<32 | ~index -> top_k stable order)
  for (u32 k = 2; k <= P; k <<= 1) {
    for (u32 j = k >> 1; j > 0; j >>= 1) {
      for (u32 t = tid; t < P; t += 256) {
        u32 x = t ^ j;
        if (x > t) {
          u64 a = keys[t], b = keys[x];
          bool up = ((t & k) == 0);
          if (up ? (a < b) : (a > b)) { keys[t] = b; keys[x] = a; }
        }
      }
      __syncthreads();
    }
  }
  // take top-200, decode boxes
  bool valid = false;
  float4 bx = make_float4(0.f, 0.f, 0.f, 0.f);
  float sc = 0.f;
  if (tid < TOPK) {
    u64 key = keys[tid];
    sc = __uint_as_float((u32)(key >> 32));
    valid = (sc > 0.01f);
    if (valid) {
      u32 idx = 0xFFFFFFFFu - (u32)(key & 0xFFFFFFFFull);
      float4 l = ((const float4*)loc)[(size_t)img * NPRI + idx];
      float4 p = ((const float4*)priors)[idx];
      float cx = p.x + (l.x * 0.1f) * p.z;
      float cy = p.y + (l.y * 0.1f) * p.w;
      float w  = p.z * expf(l.z * 0.2f);
      float h  = p.w * expf(l.w * 0.2f);
      bx = make_float4(cx - w * 0.5f, cy - h * 0.5f, cx + w * 0.5f, cy + h * 0.5f);
    }
    sbox[tid] = bx;
    sscore[tid] = sc;
  }
  u64 bal = __ballot(valid);
  if ((tid & 63) == 0) sact[tid >> 6] = bal;
  __syncthreads();
  // all-pairs suppression masks (suppress when !(iou <= 0.45); NaN suppresses)
  if (tid < TOPK) {
    float4 bi = sbox[tid];
    float ai = (bi.z - bi.x) * (bi.w - bi.y);
    u64 m0 = 0, m1 = 0, m2 = 0, m3 = 0;
    for (int j = 0; j < TOPK; ++j) {
      float4 bj = sbox[j];
      float ltx = fmaxf(bi.x, bj.x), lty = fmaxf(bi.y, bj.y);
      float rbx = fminf(bi.z, bj.z), rby = fminf(bi.w, bj.w);
      float w = fmaxf(rbx - ltx, 0.f), h = fmaxf(rby - lty, 0.f);
      float inter = w * h;
      float aj = (bj.z - bj.x) * (bj.w - bj.y);
      float uni = ai + aj - inter;
      float iou = inter / uni;
      if (!(iou <= 0.45f)) {
        if      (j < 64)  m0 |= 1ull << j;
        else if (j < 128) m1 |= 1ull << (j - 64);
        else if (j < 192) m2 |= 1ull << (j - 128);
        else              m3 |= 1ull << (j - 192);
      }
    }
    sovl[tid][0] = m0; sovl[tid][1] = m1; sovl[tid][2] = m2; sovl[tid][3] = m3;
  }
  __syncthreads();
  if (tid == 0) {
    u64 a0 = sact[0], a1 = sact[1], a2 = sact[2], a3 = sact[3];
    int K = 0;
    for (int i2 = 0; i2 < TOPK; ++i2) {
      u64 r0 = sovl[i2][0], r1 = sovl[i2][1], r2 = sovl[i2][2], r3 = sovl[i2][3];
      u64 w = (i2 & 64) ? ((i2 & 128) ? a3 : a1) : ((i2 & 128) ? a2 : a0);
      if ((w >> (i2 & 63)) & 1ull) {
        skept[K++] = (u32)i2;
        a0 &= ~r0; a1 &= ~r1; a2 &= ~r2; a3 &= ~r3;
      }
    }
    sK = (u32)K;
  }
  __syncthreads();
  if (tid < (int)sK) {
    u32 slot = skept[tid];
    float4 b = sbox[slot];
    size_t base = (((size_t)img * 2 + 1) * TOPK + (size_t)tid) * 5;
    out[base + 0] = sscore[slot];
    out[base + 1] = b.x; out[base + 2] = b.y;
    out[base + 3] = b.z; out[base + 4] = b.w;
  }
}

extern "C" void kernel_launch(void* const* d_in, const int* in_sizes, int n_in,
                              void* d_out, int out_size, void* d_ws, size_t ws_size,
                              hipStream_t stream) {
  const float* loc    = (const float*)d_in[0];
  const float* conf   = (const float*)d_in[1];
  const float* priors = (const float*)d_in[2];
  float* out = (float*)d_out;

  u32* wsw    = (u32*)d_ws;
  u32* hist   = wsw + W_HIST;
  u32* ncand  = wsw + W_NCAND;
  u32* cnt001 = wsw + W_CNT001;
  u32* flags  = wsw + W_FLAGS;
  u32* thrbin = wsw + W_THR;
  u64* cand   = (u64*)(wsw + ZWORDS);   // ZWORDS*4 is 8B-aligned

  k_zero    <<<1024, 256, 0, stream>>>(wsw, out);
  k_cap     <<<dim3(32, BATCH), 256, 0, stream>>>(conf, ncand, cnt001, cand, flags);
  k_flag    <<<1, 64, 0, stream>>>(ncand, cnt001, flags);
  k_hist2   <<<dim3(32, BATCH), 256, 0, stream>>>(conf, flags, hist);
  k_thresh2 <<<BATCH, 256, 0, stream>>>(hist, flags, thrbin);
  k_compact2<<<dim3(64, BATCH), 256, 0, stream>>>(conf, flags, thrbin, ncand, cand);
  k_nms     <<<BATCH, 256, 0, stream>>>(loc, priors, ncand, cand, out);
}

// Round 4
// 94.996 us; speedup vs baseline: 4.1676x; 2.7240x over previous
//
#include <hip/hip_runtime.h>

typedef unsigned int u32;
typedef unsigned long long u64;

#define BATCH 32
#define NPRI  200000
#define TOPK  200
#define NBINS 16384            // fallback histogram bins: bin = float_bits >> 17
#define CAP   4096             // max candidates per image
#define PRE_BITS 0x3F7C0000u   // bits of 0.984375f; capture scores >= this
#define LBUF  512              // per-block LDS candidate buffer
#define S16   16               // counter padding (64B lines)

// ws layout (u32 words)
#define W_HIST   0
#define W_NCAND  (BATCH*NBINS)
#define W_CNT001 (W_NCAND + BATCH*S16)
#define W_FLAGS  (W_CNT001 + BATCH*S16)
#define W_THR    (W_FLAGS + BATCH)
#define ZWORDS   (W_THR + BATCH)
#define OUTN     (BATCH*2*TOPK*5)

// ---------------- zero ws + output ----------------
__global__ void k_zero(u32* __restrict__ wsw, float* __restrict__ out) {
  int stride = gridDim.x * blockDim.x;
  for (int i = blockIdx.x*blockDim.x + threadIdx.x; i < ZWORDS + OUTN; i += stride) {
    if (i < ZWORDS) wsw[i] = 0u;
    else out[i - ZWORDS] = 0.0f;
  }
}

// ------- hot path: single BW pass, capture scores >= 0.984375, count positives -------
__global__ __launch_bounds__(256) void k_cap(const float* __restrict__ conf,
                                             u32* __restrict__ ncand,
                                             u32* __restrict__ cnt001,
                                             u64* __restrict__ cand,
                                             u32* __restrict__ flags) {
  __shared__ u64 lbuf[LBUF];          // 4 KB
  __shared__ u32 lcnt, lbase, lc001;
  if (threadIdx.x == 0) { lcnt = 0u; lc001 = 0u; }
  __syncthreads();
  const int img = blockIdx.y;
  const float4* cp = ((const float4*)conf) + (size_t)img * (NPRI/2);
  u32 my001 = 0;
  for (int i = blockIdx.x*256 + threadIdx.x; i < NPRI/2; i += gridDim.x*256) {
    float4 v = cp[i];
    if (v.y > 0.01f) {
      ++my001;
      u32 bits = __float_as_uint(v.y);
      if (bits >= PRE_BITS) {
        u32 p = atomicAdd(&lcnt, 1u);
        if (p < LBUF) lbuf[p] = ((u64)bits << 32) | (u64)(0xFFFFFFFFu - (u32)(2*i));
      }
    }
    if (v.w > 0.01f) {
      ++my001;
      u32 bits = __float_as_uint(v.w);
      if (bits >= PRE_BITS) {
        u32 p = atomicAdd(&lcnt, 1u);
        if (p < LBUF) lbuf[p] = ((u64)bits << 32) | (u64)(0xFFFFFFFFu - (u32)(2*i+1));
      }
    }
  }
  atomicAdd(&lc001, my001);
  __syncthreads();
  if (threadIdx.x == 0) {
    atomicAdd(&cnt001[img * S16], lc001);
    u32 n = lcnt;
    if (n > LBUF) { n = LBUF; atomicOr(&flags[img], 1u); }
    lbase = atomicAdd(&ncand[img * S16], n);
    lcnt = n;
  }
  __syncthreads();
  u64* cd = cand + (size_t)img * CAP;
  u32 n = lcnt, base = lbase;
  for (u32 t = threadIdx.x; t < n; t += 256) {
    u32 p = base + t;
    if (p < CAP) cd[p] = lbuf[t];
    else atomicOr(&flags[img], 1u);
  }
}

// ------- decide per-image fallback (tiny) -------
__global__ void k_flag(u32* __restrict__ ncand, const u32* __restrict__ cnt001,
                       u32* __restrict__ flags) {
  int img = threadIdx.x;
  if (img < BATCH) {
    u32 nc = ncand[img * S16];
    u32 c1 = cnt001[img * S16];
    if (flags[img] != 0u || (nc < TOPK && nc < c1)) {
      flags[img] = 1u;
      ncand[img * S16] = 0u;        // fallback will recapture
    } else {
      flags[img] = 0u;
    }
  }
}

// ------- fallback histogram (gated; no-op on this data) -------
__global__ __launch_bounds__(256) void k_hist2(const float* __restrict__ conf,
                                               const u32* __restrict__ flags,
                                               u32* __restrict__ hist) {
  const int img = blockIdx.y;
  if (flags[img] == 0u) return;             // uniform per block
  __shared__ u32 lh[NBINS/2];               // 32 KB, packed u16 pairs
  for (int b = threadIdx.x; b < NBINS/2; b += 256) lh[b] = 0u;
  __syncthreads();
  const float4* cp = ((const float4*)conf) + (size_t)img * (NPRI/2);
  for (int i = blockIdx.x*256 + threadIdx.x; i < NPRI/2; i += gridDim.x*256) {
    float4 v = cp[i];
    if (v.y > 0.01f) { u32 b = __float_as_uint(v.y) >> 17; atomicAdd(&lh[b >> 1], 1u << ((b & 1) * 16)); }
    if (v.w > 0.01f) { u32 b = __float_as_uint(v.w) >> 17; atomicAdd(&lh[b >> 1], 1u << ((b & 1) * 16)); }
  }
  __syncthreads();
  u32* h = hist + (size_t)img * NBINS;
  for (int b = threadIdx.x; b < NBINS/2; b += 256) {
    u32 v = lh[b];
    if (v & 0xFFFFu) atomicAdd(&h[2*b],     v & 0xFFFFu);
    if (v >> 16)     atomicAdd(&h[2*b + 1], v >> 16);
  }
}

// ------- fallback exact threshold bin (gated) -------
__global__ __launch_bounds__(256) void k_thresh2(const u32* __restrict__ hist,
                                                 const u32* __restrict__ flags,
                                                 u32* __restrict__ thrbin) {
  const int img = blockIdx.x;
  const int tid = threadIdx.x;
  if (flags[img] == 0u) { if (tid == 0) thrbin[img] = 0u; return; }
  const u32* h = hist + (size_t)img * NBINS;
  __shared__ u32 sums[256], binv[64];
  __shared__ u32 s_c, s_above;
  u32 acc = 0;
  for (int b = 0; b < 64; ++b) acc += h[tid*64 + b];
  sums[tid] = acc;
  if (tid == 0) s_c = 0xFFFFFFFFu;
  __syncthreads();
  for (int off = 1; off < 256; off <<= 1) {
    u32 v = (tid + off < 256) ? sums[tid + off] : 0u;
    __syncthreads();
    sums[tid] += v;
    __syncthreads();
  }
  u32 mine = sums[tid], nxt = (tid < 255) ? sums[tid + 1] : 0u;
  if (mine >= TOPK && nxt < TOPK) { s_c = tid; s_above = nxt; }
  __syncthreads();
  if (s_c == 0xFFFFFFFFu) { if (tid == 0) thrbin[img] = 0u; return; }
  if (tid < 64) binv[tid] = h[s_c*64 + tid];
  __syncthreads();
  if (tid == 0) {
    u32 run = s_above, T = 0u;
    for (int b = 63; b >= 0; --b) {
      run += binv[b];
      if (run >= TOPK) { T = s_c*64 + (u32)b; break; }
    }
    thrbin[img] = T;
  }
}

// ------- fallback capture >= threshold bin (gated) -------
__global__ __launch_bounds__(256) void k_compact2(const float* __restrict__ conf,
                                                  const u32* __restrict__ flags,
                                                  const u32* __restrict__ thrbin,
                                                  u32* __restrict__ ncand,
                                                  u64* __restrict__ cand) {
  const int img = blockIdx.y;
  if (flags[img] == 0u) return;
  const u32 T = thrbin[img];
  __shared__ u64 lbuf[1024];          // 8 KB
  __shared__ u32 lcnt, lbase;
  if (threadIdx.x == 0) lcnt = 0u;
  __syncthreads();
  const float4* cp = ((const float4*)conf) + (size_t)img * (NPRI/2);
  u64* cd = cand + (size_t)img * CAP;
  for (int i = blockIdx.x*256 + threadIdx.x; i < NPRI/2; i += gridDim.x*256) {
    float4 v = cp[i];
    if (v.y > 0.01f) {
      u32 bits = __float_as_uint(v.y);
      if ((bits >> 17) >= T) {
        u32 p = atomicAdd(&lcnt, 1u);
        if (p < 1024) lbuf[p] = ((u64)bits << 32) | (u64)(0xFFFFFFFFu - (u32)(2*i));
      }
    }
    if (v.w > 0.01f) {
      u32 bits = __float_as_uint(v.w);
      if ((bits >> 17) >= T) {
        u32 p = atomicAdd(&lcnt, 1u);
        if (p < 1024) lbuf[p] = ((u64)bits << 32) | (u64)(0xFFFFFFFFu - (u32)(2*i+1));
      }
    }
  }
  __syncthreads();
  if (threadIdx.x == 0) {
    u32 n = lcnt; if (n > 1024u) n = 1024u;
    lbase = atomicAdd(&ncand[img * S16], n);
    lcnt = n;
  }
  __syncthreads();
  u32 n = lcnt, base = lbase;
  for (u32 t = threadIdx.x; t < n; t += 256) {
    u32 p = base + t;
    if (p < CAP) cd[p] = lbuf[t];
  }
}

// ---------------- radix-select + small sort + NMS + emit ----------------
// LDS map (aliased, 53248 B static):
//   [0,32768)        u64 keys[4096]
//   [32768,49152)    u32 lh[4096]         -- later reused for sbox/sscore/skept/sovl/sact
//   [49152,53248)    u32 csum[1024]       -- later reused as u64 skeys[512]
__global__ __launch_bounds__(1024) void k_nms(const float* __restrict__ loc,
                                              const float* __restrict__ priors,
                                              const u32* __restrict__ ncand,
                                              const u64* __restrict__ cand,
                                              float* __restrict__ out) {
  __shared__ __align__(16) char smem[53248];
  u64* keys = (u64*)smem;
  u32* lh   = (u32*)(smem + 32768);
  u32* csum = (u32*)(smem + 49152);
  u64* skeys = (u64*)(smem + 49152);
  float4* sbox  = (float4*)(smem + 32768);
  float*  sscore = (float*)(smem + 32768 + 3200);
  u32*    skept  = (u32*)(smem + 32768 + 4000);
  u64*    sovl   = (u64*)(smem + 32768 + 4800);   // [200][4]
  u64*    sact   = (u64*)(smem + 32768 + 11200);  // [4]
  __shared__ u32 s_TB, s_SC, s_scnt, s_K;

  const int img = blockIdx.x;
  const int tid = threadIdx.x;
  u32 nc = ncand[img * S16]; if (nc > CAP) nc = CAP;
  if (nc == 0) return;                       // uniform; out pre-zeroed
  const u32 K = (nc < TOPK) ? nc : TOPK;
  const u64* cd = cand + (size_t)img * CAP;

  // load keys (pad to 4096) + zero histogram
  #pragma unroll
  for (int t = tid; t < CAP; t += 1024) {
    keys[t] = (t < (int)nc) ? cd[t] : 0ull;
    lh[t] = 0u;
  }
  if (tid == 0) { s_TB = 0u; s_SC = 0u; s_scnt = 0u; }
  __syncthreads();

  // histogram on score bits; bins monotone in score for bits >= PRE_BITS
  #pragma unroll
  for (int t = tid; t < CAP; t += 1024) {
    if (t < (int)nc) {
      u32 bits = (u32)(keys[t] >> 32);
      u32 bin = (bits >= PRE_BITS) ? ((bits - PRE_BITS) >> 6) : 0u;
      atomicAdd(&lh[bin], 1u);
    }
  }
  __syncthreads();
  // chunk sums (4 bins/thread) + inclusive suffix scan over 1024 chunks
  csum[tid] = lh[4*tid] + lh[4*tid+1] + lh[4*tid+2] + lh[4*tid+3];
  __syncthreads();
  for (int off = 1; off < 1024; off <<= 1) {
    u32 v = (tid + off < 1024) ? csum[tid + off] : 0u;
    __syncthreads();
    csum[tid] += v;
    __syncthreads();
  }
  {
    u32 mine = csum[tid], nxt = (tid < 1023) ? csum[tid + 1] : 0u;
    if (mine >= K && nxt < K) {              // unique boundary chunk
      u32 run = nxt;
      for (int b = 3; b >= 0; --b) {
        run += lh[tid*4 + b];
        if (run >= K) { s_TB = (u32)(tid*4 + b); s_SC = run; break; }
      }
    }
  }
  __syncthreads();
  const u32 TB = s_TB, SC = s_SC;
  const bool generic = (SC > 512u) || (SC < K);   // ties overflow / degenerate
  u32 P2;

  if (!generic) {
    // compact survivors (bin >= TB) into skeys (aliases csum; csum dead now)
    #pragma unroll
    for (int t = tid; t < CAP; t += 1024) {
      if (t < (int)nc) {
        u64 key = keys[t];
        u32 bits = (u32)(key >> 32);
        u32 bin = (bits >= PRE_BITS) ? ((bits - PRE_BITS) >> 6) : 0u;
        if (bin >= TB) { u32 p = atomicAdd(&s_scnt, 1u); skeys[p] = key; }
      }
    }
    __syncthreads();
    P2 = (SC <= 256u) ? 256u : 512u;
    for (u32 t = tid; t < P2; t += 1024) if (t >= SC) skeys[t] = 0ull;
    __syncthreads();
    // bitonic sort descending, P2 <= 512, one slot per thread
    for (u32 k = 2; k <= P2; k <<= 1) {
      for (u32 j = k >> 1; j > 0; j >>= 1) {
        u32 t = (u32)tid;
        if (t < P2) {
          u32 x = t ^ j;
          if (x > t) {
            u64 a = skeys[t], b = skeys[x];
            bool up = ((t & k) == 0);
            if (up ? (a < b) : (a > b)) { skeys[t] = b; skeys[x] = a; }
          }
        }
        __syncthreads();
      }
    }
  } else {
    // generic: full bitonic over 4096 (constant trip count -> unrolled, batched)
    for (u32 k = 2; k <= CAP; k <<= 1) {
      for (u32 j = k >> 1; j > 0; j >>= 1) {
        #pragma unroll
        for (u32 t = tid; t < CAP; t += 1024) {
          u32 x = t ^ j;
          if (x > t) {
            u64 a = keys[t], b = keys[x];
            bool up = ((t & k) == 0);
            if (up ? (a < b) : (a > b)) { keys[t] = b; keys[x] = a; }
          }
        }
        __syncthreads();
      }
    }
    // copy top 512 into skeys so later phases are uniform
    if (tid < 512) skeys[tid] = keys[tid];
    __syncthreads();
  }

  // ---- decode top-200 (sbox region aliases lh; lh dead now) ----
  bool valid = false;
  float4 bx = make_float4(0.f, 0.f, 0.f, 0.f);
  float sc = 0.f;
  if (tid < TOPK) {
    u64 key = skeys[tid];
    sc = __uint_as_float((u32)(key >> 32));
    valid = (sc > 0.01f);
    if (valid) {
      u32 idx = 0xFFFFFFFFu - (u32)(key & 0xFFFFFFFFull);
      float4 l = ((const float4*)loc)[(size_t)img * NPRI + idx];
      float4 p = ((const float4*)priors)[idx];
      float cx = p.x + (l.x * 0.1f) * p.z;
      float cy = p.y + (l.y * 0.1f) * p.w;
      float w  = p.z * expf(l.z * 0.2f);
      float h  = p.w * expf(l.w * 0.2f);
      bx = make_float4(cx - w * 0.5f, cy - h * 0.5f, cx + w * 0.5f, cy + h * 0.5f);
    }
  }
  __syncthreads();                            // everyone past skeys reads
  if (tid < TOPK) { sbox[tid] = bx; sscore[tid] = sc; }
  {
    u64 bal = __ballot(valid);                // wave w covers slots [64w, 64w+64)
    if ((tid & 63) == 0 && (tid >> 6) < 4) sact[tid >> 6] = bal;
  }
  __syncthreads();
  // all-pairs suppression masks (suppress when !(iou <= 0.45); NaN suppresses)
  if (tid < TOPK) {
    float4 bi = sbox[tid];
    float ai = (bi.z - bi.x) * (bi.w - bi.y);
    u64 m0 = 0, m1 = 0, m2 = 0, m3 = 0;
    for (int j = 0; j < TOPK; ++j) {
      float4 bj = sbox[j];
      float ltx = fmaxf(bi.x, bj.x), lty = fmaxf(bi.y, bj.y);
      float rbx = fminf(bi.z, bj.z), rby = fminf(bi.w, bj.w);
      float w = fmaxf(rbx - ltx, 0.f), h = fmaxf(rby - lty, 0.f);
      float inter = w * h;
      float aj = (bj.z - bj.x) * (bj.w - bj.y);
      float uni = ai + aj - inter;
      float iou = inter / uni;
      if (!(iou <= 0.45f)) {
        if      (j < 64)  m0 |= 1ull << j;
        else if (j < 128) m1 |= 1ull << (j - 64);
        else if (j < 192) m2 |= 1ull << (j - 128);
        else              m3 |= 1ull << (j - 192);
      }
    }
    sovl[tid*4+0] = m0; sovl[tid*4+1] = m1; sovl[tid*4+2] = m2; sovl[tid*4+3] = m3;
  }
  __syncthreads();
  if (tid == 0) {
    u64 a0 = sact[0], a1 = sact[1], a2 = sact[2], a3 = sact[3];
    int Kk = 0;
    for (int i2 = 0; i2 < TOPK; ++i2) {
      u64 w = (i2 & 64) ? ((i2 & 128) ? a3 : a1) : ((i2 & 128) ? a2 : a0);
      if ((w >> (i2 & 63)) & 1ull) {
        skept[Kk++] = (u32)i2;
        a0 &= ~sovl[i2*4+0]; a1 &= ~sovl[i2*4+1];
        a2 &= ~sovl[i2*4+2]; a3 &= ~sovl[i2*4+3];
      }
    }
    s_K = (u32)Kk;
  }
  __syncthreads();
  if (tid < (int)s_K) {
    u32 slot = skept[tid];
    float4 b = sbox[slot];
    size_t base = (((size_t)img * 2 + 1) * TOPK + (size_t)tid) * 5;
    out[base + 0] = sscore[slot];
    out[base + 1] = b.x; out[base + 2] = b.y;
    out[base + 3] = b.z; out[base + 4] = b.w;
  }
}

extern "C" void kernel_launch(void* const* d_in, const int* in_sizes, int n_in,
                              void* d_out, int out_size, void* d_ws, size_t ws_size,
                              hipStream_t stream) {
  const float* loc    = (const float*)d_in[0];
  const float* conf   = (const float*)d_in[1];
  const float* priors = (const float*)d_in[2];
  float* out = (float*)d_out;

  u32* wsw    = (u32*)d_ws;
  u32* hist   = wsw + W_HIST;
  u32* ncand  = wsw + W_NCAND;
  u32* cnt001 = wsw + W_CNT001;
  u32* flags  = wsw + W_FLAGS;
  u32* thrbin = wsw + W_THR;
  u64* cand   = (u64*)(wsw + ZWORDS);   // ZWORDS*4 is 8B-aligned

  k_zero    <<<1024, 256, 0, stream>>>(wsw, out);
  k_cap     <<<dim3(32, BATCH), 256, 0, stream>>>(conf, ncand, cnt001, cand, flags);
  k_flag    <<<1, 64, 0, stream>>>(ncand, cnt001, flags);
  k_hist2   <<<dim3(32, BATCH), 256, 0, stream>>>(conf, flags, hist);
  k_thresh2 <<<BATCH, 256, 0, stream>>>(hist, flags, thrbin);
  k_compact2<<<dim3(64, BATCH), 256, 0, stream>>>(conf, flags, thrbin, ncand, cand);
  k_nms     <<<BATCH, 1024, 0, stream>>>(loc, priors, ncand, cand, out);
}